// Round 1
// baseline (11352.383 us; speedup 1.0000x reference)
//
#include <hip/hip_runtime.h>
#include <hip/hip_bf16.h>
#include <math.h>

// Problem constants
#define I_DIM 64
#define H_DIM 256
#define NC    10
#define S1    500
#define S2    41
#define BATCH 128
#define ST    (S1 + S2)          // 541
#define F1    (ST * H_DIM)       // 138496
#define G4H   (4 * H_DIM)        // 1024
#define KTOT  (I_DIM + H_DIM)    // 320
#define K4TOT (KTOT / 4)         // 80

// fc1 split-K params
#define KC   512
#define KCH  32
#define NSLICE ((F1 + KC - 1) / KC)   // 271

__device__ __forceinline__ float sigmoidf(float x) {
    return 1.0f / (1.0f + expf(-x));
}

// ---------------------------------------------------------------------------
// Pack combined [w_ih | w_hh] weights into k-major float4 layout:
//   Wp[l][k4][g] = float4( wcat[g][4k4 .. 4k4+3] ),  wcat = [w_ih (k<64) | w_hh]
// Also bsum[l][g] = b_ih[g] + b_hh[g].
// ---------------------------------------------------------------------------
__global__ void prep_pack(const float* __restrict__ wih1, const float* __restrict__ whh1,
                          const float* __restrict__ bih1, const float* __restrict__ bhh1,
                          const float* __restrict__ wih2, const float* __restrict__ whh2,
                          const float* __restrict__ bih2, const float* __restrict__ bhh2,
                          float4* __restrict__ Wp, float* __restrict__ bsum) {
    int gid = blockIdx.x * blockDim.x + threadIdx.x;   // 0..2047
    if (gid >= 2 * G4H) return;
    int l = gid >> 10;
    int g = gid & (G4H - 1);
    const float* wih = l ? wih2 : wih1;
    const float* whh = l ? whh2 : whh1;
    float4* dst = Wp + (size_t)l * K4TOT * G4H;
    for (int k4 = 0; k4 < K4TOT; ++k4) {
        int k = k4 * 4;
        float4 v;
        if (k < I_DIM) {
            const float* p = wih + (size_t)g * I_DIM + k;
            v = make_float4(p[0], p[1], p[2], p[3]);
        } else {
            const float* p = whh + (size_t)g * H_DIM + (k - I_DIM);
            v = make_float4(p[0], p[1], p[2], p[3]);
        }
        dst[(size_t)k4 * G4H + g] = v;
    }
    bsum[gid] = l ? (bih2[g] + bhh2[g]) : (bih1[g] + bhh1[g]);
}

// ---------------------------------------------------------------------------
// Fused peephole LSTM: each block owns 2 batch elements for the whole sequence.
// Blocks 0..63 -> LSTM1 (T=500), blocks 64..127 -> LSTM2 (T=41).
// Thread u (0..255) owns hidden unit u: gate rows {u, u+256, u+512, u+768}.
// h double-buffered in LDS; c in registers. Writes hseq[b][toff+t][u].
// ---------------------------------------------------------------------------
__global__ __launch_bounds__(256) void lstm_fused(
        const float* __restrict__ x1, const float* __restrict__ x2,
        const float* __restrict__ wci1, const float* __restrict__ wcf1, const float* __restrict__ wco1,
        const float* __restrict__ wci2, const float* __restrict__ wcf2, const float* __restrict__ wco2,
        const float4* __restrict__ Wp, const float* __restrict__ bsum,
        float* __restrict__ hseq) {
    const int wg  = blockIdx.x;       // 0..127
    const int l   = wg >> 6;          // 0 or 1
    const int grp = wg & 63;
    const int b0  = grp * 2;
    const int T    = l ? S2 : S1;
    const int toff = l ? S1 : 0;
    const float* x = l ? x2 : x1;
    const float* wci = l ? wci2 : wci1;
    const float* wcf = l ? wcf2 : wcf1;
    const float* wco = l ? wco2 : wco1;
    const float4* W = Wp + (size_t)l * K4TOT * G4H;

    const int u = threadIdx.x;        // hidden unit

    __shared__ __align__(16) float xsf[2][I_DIM];        // current x_t, 2 batch
    __shared__ __align__(16) float hsf[2][2][H_DIM];     // double-buffered h

    // init h = 0 (both buffers)
    {
        int idx = u;                   // 256 threads cover 2*2*256/4 via float writes
        hsf[0][0][idx] = 0.f; hsf[0][1][idx] = 0.f;
        hsf[1][0][idx] = 0.f; hsf[1][1][idx] = 0.f;
    }

    float c0 = 0.f, c1 = 0.f;
    const float pi = wci[u], pf = wcf[u], po = wco[u];
    const float bi = bsum[l * G4H + u];
    const float bf = bsum[l * G4H + u + 256];
    const float bg = bsum[l * G4H + u + 512];
    const float bo = bsum[l * G4H + u + 768];

    const float4* Wr = W + u;   // this thread's row base (gate i); +256/+512/+768 for f/c/o
    int cur = 0;
    __syncthreads();

    for (int t = 0; t < T; ++t) {
        // stage x_t for both batch elems (2 * 16 float4)
        if (u < 32) {
            int bb = u >> 4, k4 = u & 15;
            const float4* xp = (const float4*)(x + ((size_t)(b0 + bb) * T + t) * I_DIM);
            ((float4*)xsf[bb])[k4] = xp[k4];
        }
        __syncthreads();

        float a00 = bi, a01 = bf, a02 = bg, a03 = bo;   // batch 0
        float a10 = bi, a11 = bf, a12 = bg, a13 = bo;   // batch 1

        const float4* xs0 = (const float4*)xsf[0];
        const float4* xs1 = (const float4*)xsf[1];
        const float4* h0  = (const float4*)hsf[cur][0];
        const float4* h1  = (const float4*)hsf[cur][1];

        // x part: k4 = 0..15
        #pragma unroll 4
        for (int k4 = 0; k4 < 16; ++k4) {
            const float4* p = Wr + (size_t)k4 * G4H;
            float4 w0 = p[0], w1 = p[256], w2 = p[512], w3 = p[768];
            float4 v0 = xs0[k4], v1 = xs1[k4];
            a00 = fmaf(w0.x, v0.x, fmaf(w0.y, v0.y, fmaf(w0.z, v0.z, fmaf(w0.w, v0.w, a00))));
            a01 = fmaf(w1.x, v0.x, fmaf(w1.y, v0.y, fmaf(w1.z, v0.z, fmaf(w1.w, v0.w, a01))));
            a02 = fmaf(w2.x, v0.x, fmaf(w2.y, v0.y, fmaf(w2.z, v0.z, fmaf(w2.w, v0.w, a02))));
            a03 = fmaf(w3.x, v0.x, fmaf(w3.y, v0.y, fmaf(w3.z, v0.z, fmaf(w3.w, v0.w, a03))));
            a10 = fmaf(w0.x, v1.x, fmaf(w0.y, v1.y, fmaf(w0.z, v1.z, fmaf(w0.w, v1.w, a10))));
            a11 = fmaf(w1.x, v1.x, fmaf(w1.y, v1.y, fmaf(w1.z, v1.z, fmaf(w1.w, v1.w, a11))));
            a12 = fmaf(w2.x, v1.x, fmaf(w2.y, v1.y, fmaf(w2.z, v1.z, fmaf(w2.w, v1.w, a12))));
            a13 = fmaf(w3.x, v1.x, fmaf(w3.y, v1.y, fmaf(w3.z, v1.z, fmaf(w3.w, v1.w, a13))));
        }
        // h part: k4 = 16..79
        #pragma unroll 4
        for (int k4 = 0; k4 < 64; ++k4) {
            const float4* p = Wr + (size_t)(k4 + 16) * G4H;
            float4 w0 = p[0], w1 = p[256], w2 = p[512], w3 = p[768];
            float4 v0 = h0[k4], v1 = h1[k4];
            a00 = fmaf(w0.x, v0.x, fmaf(w0.y, v0.y, fmaf(w0.z, v0.z, fmaf(w0.w, v0.w, a00))));
            a01 = fmaf(w1.x, v0.x, fmaf(w1.y, v0.y, fmaf(w1.z, v0.z, fmaf(w1.w, v0.w, a01))));
            a02 = fmaf(w2.x, v0.x, fmaf(w2.y, v0.y, fmaf(w2.z, v0.z, fmaf(w2.w, v0.w, a02))));
            a03 = fmaf(w3.x, v0.x, fmaf(w3.y, v0.y, fmaf(w3.z, v0.z, fmaf(w3.w, v0.w, a03))));
            a10 = fmaf(w0.x, v1.x, fmaf(w0.y, v1.y, fmaf(w0.z, v1.z, fmaf(w0.w, v1.w, a10))));
            a11 = fmaf(w1.x, v1.x, fmaf(w1.y, v1.y, fmaf(w1.z, v1.z, fmaf(w1.w, v1.w, a11))));
            a12 = fmaf(w2.x, v1.x, fmaf(w2.y, v1.y, fmaf(w2.z, v1.z, fmaf(w2.w, v1.w, a12))));
            a13 = fmaf(w3.x, v1.x, fmaf(w3.y, v1.y, fmaf(w3.z, v1.z, fmaf(w3.w, v1.w, a13))));
        }

        // cell update, batch 0
        {
            float i_ = sigmoidf(a00 + pi * c0);
            float f_ = sigmoidf(a01 + pf * c0);
            float g_ = tanhf(a02);
            float cy = f_ * c0 + i_ * g_;
            float o_ = sigmoidf(a03 + po * cy);
            float hy = o_ * tanhf(cy);
            c0 = cy;
            hsf[cur ^ 1][0][u] = hy;
            hseq[((size_t)(b0 + 0) * ST + toff + t) * H_DIM + u] = hy;
        }
        // cell update, batch 1
        {
            float i_ = sigmoidf(a10 + pi * c1);
            float f_ = sigmoidf(a11 + pf * c1);
            float g_ = tanhf(a12);
            float cy = f_ * c1 + i_ * g_;
            float o_ = sigmoidf(a13 + po * cy);
            float hy = o_ * tanhf(cy);
            c1 = cy;
            hsf[cur ^ 1][1][u] = hy;
            hseq[((size_t)(b0 + 1) * ST + toff + t) * H_DIM + u] = hy;
        }
        __syncthreads();
        cur ^= 1;
    }
}

// ---------------------------------------------------------------------------
// fc1 split-K partial GEMM: out1[b][j] partial over k-slice s.
// Tile: full [128 x 128] output per block, K-slice of 512.
// part[s][b][j] += sum_{k in slice} hseq[b][k] * fc1_w[j][k]
// ---------------------------------------------------------------------------
__global__ __launch_bounds__(256) void fc1_partial(const float* __restrict__ hseq,
                                                   const float* __restrict__ w,
                                                   float* __restrict__ part) {
    const int s  = blockIdx.x;          // 0..NSLICE-1
    const int k0 = s * KC;
    const int kend = (k0 + KC < F1) ? (k0 + KC) : F1;

    __shared__ float As[KCH][129];      // As[k][b]
    __shared__ float Bs[KCH][129];      // Bs[k][j]

    const int tid = threadIdx.x;
    const int tx = tid & 15;            // j block
    const int ty = tid >> 4;            // b block

    float acc[8][8];
    #pragma unroll
    for (int i = 0; i < 8; ++i)
        #pragma unroll
        for (int j = 0; j < 8; ++j) acc[i][j] = 0.f;

    for (int kk = k0; kk < kend; kk += KCH) {
        // stage 128 rows x 32 k of both arrays
        #pragma unroll
        for (int r = 0; r < 16; ++r) {
            int idx = r * 256 + tid;    // 0..4095
            int row = idx >> 5;
            int k   = idx & 31;
            int gk  = kk + k;
            float av = (gk < F1) ? hseq[(size_t)row * F1 + gk] : 0.f;
            float bv = (gk < F1) ? w[(size_t)row * F1 + gk] : 0.f;
            As[k][row] = av;
            Bs[k][row] = bv;
        }
        __syncthreads();

        #pragma unroll 8
        for (int k = 0; k < KCH; ++k) {
            float av[8], bv[8];
            #pragma unroll
            for (int i = 0; i < 8; ++i) av[i] = As[k][ty * 8 + i];
            #pragma unroll
            for (int j = 0; j < 8; ++j) bv[j] = Bs[k][tx * 8 + j];
            #pragma unroll
            for (int i = 0; i < 8; ++i)
                #pragma unroll
                for (int j = 0; j < 8; ++j)
                    acc[i][j] = fmaf(av[i], bv[j], acc[i][j]);
        }
        __syncthreads();
    }

    float* dst = part + (size_t)s * (BATCH * 128);
    #pragma unroll
    for (int i = 0; i < 8; ++i)
        #pragma unroll
        for (int j = 0; j < 8; ++j)
            dst[(size_t)(ty * 8 + i) * 128 + (tx * 8 + j)] = acc[i][j];
}

// ---------------------------------------------------------------------------
// reduce partials + bias + relu -> out1[b][j]
// ---------------------------------------------------------------------------
__global__ __launch_bounds__(256) void fc1_reduce(const float* __restrict__ part,
                                                  const float* __restrict__ fc1_b,
                                                  float* __restrict__ out1) {
    int flat = blockIdx.x * 256 + threadIdx.x;     // 0..16383
    float sum = 0.f;
    for (int i = 0; i < NSLICE; ++i)
        sum += part[(size_t)i * (BATCH * 128) + flat];
    int j = flat & 127;
    sum += fc1_b[j];
    out1[flat] = fmaxf(sum, 0.f);
}

// ---------------------------------------------------------------------------
// fc2: out[b][n] = fc_b[n] + sum_j out1[b][j] * fc_w[n][j]
// ---------------------------------------------------------------------------
__global__ __launch_bounds__(128) void fc2_kernel(const float* __restrict__ out1,
                                                  const float* __restrict__ fcw,
                                                  const float* __restrict__ fcb,
                                                  float* __restrict__ out) {
    int b = blockIdx.x;
    __shared__ float ro[128];
    int tid = threadIdx.x;
    ro[tid] = out1[(size_t)b * 128 + tid];
    __syncthreads();
    if (tid < NC) {
        float s = fcb[tid];
        #pragma unroll 8
        for (int j = 0; j < 128; ++j)
            s = fmaf(ro[j], fcw[(size_t)tid * 128 + j], s);
        out[(size_t)b * NC + tid] = s;
    }
}

// ---------------------------------------------------------------------------
extern "C" void kernel_launch(void* const* d_in, const int* in_sizes, int n_in,
                              void* d_out, int out_size, void* d_ws, size_t ws_size,
                              hipStream_t stream) {
    const float* rr_x  = (const float*)d_in[0];
    const float* rr_wv = (const float*)d_in[1];
    const float* w_ih1 = (const float*)d_in[2];
    const float* w_hh1 = (const float*)d_in[3];
    const float* b_ih1 = (const float*)d_in[4];
    const float* b_hh1 = (const float*)d_in[5];
    const float* wci1  = (const float*)d_in[6];
    const float* wcf1  = (const float*)d_in[7];
    const float* wco1  = (const float*)d_in[8];
    const float* w_ih2 = (const float*)d_in[9];
    const float* w_hh2 = (const float*)d_in[10];
    const float* b_ih2 = (const float*)d_in[11];
    const float* b_hh2 = (const float*)d_in[12];
    const float* wci2  = (const float*)d_in[13];
    const float* wcf2  = (const float*)d_in[14];
    const float* wco2  = (const float*)d_in[15];
    const float* fc1_w = (const float*)d_in[16];
    const float* fc1_b = (const float*)d_in[17];
    const float* fc_w  = (const float*)d_in[18];
    const float* fc_b  = (const float*)d_in[19];
    float* out = (float*)d_out;

    // workspace layout (all offsets 16B aligned)
    char* ws = (char*)d_ws;
    size_t off = 0;
    float4* Wp   = (float4*)(ws + off); off += (size_t)2 * K4TOT * G4H * sizeof(float4); // 2,621,440
    float*  bsum = (float*)(ws + off);  off += (size_t)2 * G4H * sizeof(float);          // 8,192
    float*  hseq = (float*)(ws + off);  off += (size_t)BATCH * F1 * sizeof(float);       // 70,909,952
    float*  part = (float*)(ws + off);  off += (size_t)NSLICE * BATCH * 128 * sizeof(float); // 17,760,256
    float*  out1 = (float*)(ws + off);  off += (size_t)BATCH * 128 * sizeof(float);      // 65,536

    prep_pack<<<8, 256, 0, stream>>>(w_ih1, w_hh1, b_ih1, b_hh1,
                                     w_ih2, w_hh2, b_ih2, b_hh2, Wp, bsum);

    lstm_fused<<<128, 256, 0, stream>>>(rr_x, rr_wv,
                                        wci1, wcf1, wco1, wci2, wcf2, wco2,
                                        Wp, bsum, hseq);

    fc1_partial<<<NSLICE, 256, 0, stream>>>(hseq, fc1_w, part);
    fc1_reduce<<<BATCH * 128 / 256, 256, 0, stream>>>(part, fc1_b, out1);
    fc2_kernel<<<BATCH, 128, 0, stream>>>(out1, fc_w, fc_b, out);
}

// Round 2
// 9468.746 us; speedup vs baseline: 1.1989x; 1.1989x over previous
//
#include <hip/hip_runtime.h>
#include <hip/hip_bf16.h>
#include <math.h>

// Problem constants
#define I_DIM 64
#define H_DIM 256
#define NC    10
#define S1    500
#define S2    41
#define BATCH 128
#define ST    (S1 + S2)          // 541
#define F1    (ST * H_DIM)       // 138496
#define G4H   (4 * H_DIM)        // 1024 gate rows
#define KTOT  (I_DIM + H_DIM)    // 320
#define K4TOT (KTOT / 4)         // 80
#define NSL   4                  // k-slices per unit
#define K4PS  (K4TOT / NSL)      // 20 float4-k iters per slice

// fc1 split-K params
#define KC   512
#define KCH  32
#define NSLICE ((F1 + KC - 1) / KC)   // 271

__device__ __forceinline__ float sigmoidf(float x) {
    return 1.0f / (1.0f + expf(-x));
}

// ---------------------------------------------------------------------------
// Pack combined [w_ih | w_hh] into k-major, gate-adjacent float4 layout:
//   Wp[l][k4][u][gate] = float4( wcat[gate*256+u][4k4 .. 4k4+3] )
// so a thread's 4 gate rows for one k4 are 64 contiguous bytes (imm-foldable).
// Also bsum[l][g] = b_ih[g] + b_hh[g].
// ---------------------------------------------------------------------------
__global__ void prep_pack(const float* __restrict__ wih1, const float* __restrict__ whh1,
                          const float* __restrict__ bih1, const float* __restrict__ bhh1,
                          const float* __restrict__ wih2, const float* __restrict__ whh2,
                          const float* __restrict__ bih2, const float* __restrict__ bhh2,
                          float4* __restrict__ Wp, float* __restrict__ bsum) {
    int gid = blockIdx.x * blockDim.x + threadIdx.x;   // 0..2047
    if (gid >= 2 * G4H) return;
    int l = gid >> 10;
    int g = gid & (G4H - 1);       // gate row 0..1023
    int gate = g >> 8;             // 0..3 (i,f,c,o)
    int u = g & 255;               // hidden unit
    const float* wih = l ? wih2 : wih1;
    const float* whh = l ? whh2 : whh1;
    float4* dst = Wp + (size_t)l * K4TOT * G4H;
    for (int k4 = 0; k4 < K4TOT; ++k4) {
        int k = k4 * 4;
        float4 v;
        if (k < I_DIM) {
            const float* p = wih + (size_t)g * I_DIM + k;
            v = make_float4(p[0], p[1], p[2], p[3]);
        } else {
            const float* p = whh + (size_t)g * H_DIM + (k - I_DIM);
            v = make_float4(p[0], p[1], p[2], p[3]);
        }
        dst[(size_t)k4 * G4H + u * 4 + gate] = v;
    }
    bsum[gid] = l ? (bih2[g] + bhh2[g]) : (bih1[g] + bhh1[g]);
}

// ---------------------------------------------------------------------------
// Fused peephole LSTM, latency-hiding version.
// Grid: 128 blocks x 1024 threads. Blocks 0..63 -> LSTM1 (2 batch each),
// blocks 64..127 -> LSTM2 (2 batch each). 16 waves/CU = 4/SIMD.
// Thread = (u = tid&255, s = tid>>8): unit u, k-slice s (20 float4-k each),
// accumulates 4 gates x 2 batches over its slice; partials reduced via LDS;
// s==0 group does the cell update. [x_t | h_{t-1}] staged in LDS (double buf).
// ---------------------------------------------------------------------------
__global__ __launch_bounds__(1024, 4) void lstm_fused(
        const float* __restrict__ x1, const float* __restrict__ x2,
        const float* __restrict__ wci1, const float* __restrict__ wcf1, const float* __restrict__ wco1,
        const float* __restrict__ wci2, const float* __restrict__ wcf2, const float* __restrict__ wco2,
        const float4* __restrict__ Wp, const float* __restrict__ bsum,
        float* __restrict__ hseq) {
    const int wg  = blockIdx.x;       // 0..127
    const int l   = wg >> 6;          // 0 or 1
    const int grp = wg & 63;
    const int b0  = grp * 2;
    const int T    = l ? S2 : S1;
    const int toff = l ? S1 : 0;
    const float* x = l ? x2 : x1;
    const float* wci = l ? wci2 : wci1;
    const float* wcf = l ? wcf2 : wcf1;
    const float* wco = l ? wco2 : wco1;

    const int tid = threadIdx.x;
    const int u = tid & 255;          // hidden unit
    const int s = tid >> 8;           // k-slice 0..3

    // vbuf[buf][batch][k]: k<64 = x_t, k>=64 = h_{t-1}
    __shared__ __align__(16) float vbuf[2][2][KTOT];
    // partial gate sums from slices 1..3: part[s-1][b][gate][u]
    __shared__ float part[NSL - 1][2][4][H_DIM];

    // zero both buffers (h region must be 0 at t=0)
    for (int i = tid; i < 2 * 2 * KTOT; i += 1024) ((float*)vbuf)[i] = 0.f;
    __syncthreads();
    // stage x_0
    if (tid < 32) {
        int bb = tid >> 4, k4 = tid & 15;
        float4 v = *(const float4*)(x + ((size_t)(b0 + bb) * T + 0) * I_DIM + 4 * k4);
        *((float4*)&vbuf[0][bb][4 * k4]) = v;
    }

    // per-unit constants (used by s==0 group)
    const float pi = wci[u], pf = wcf[u], po = wco[u];
    const float bI = bsum[l * G4H + u];
    const float bF = bsum[l * G4H + u + 256];
    const float bG = bsum[l * G4H + u + 512];
    const float bO = bsum[l * G4H + u + 768];

    // this thread's weight base: slice start, unit u, gate 0
    const float4* Wbase = Wp + (size_t)l * K4TOT * G4H
                             + (size_t)(K4PS * s) * G4H + (size_t)u * 4;

    float c0 = 0.f, c1 = 0.f;
    int cur = 0;
    __syncthreads();

    for (int t = 0; t < T; ++t) {
        float acc[4][2];
        #pragma unroll
        for (int g = 0; g < 4; ++g) { acc[g][0] = 0.f; acc[g][1] = 0.f; }

        const float4* vb0 = (const float4*)vbuf[cur][0];
        const float4* vb1 = (const float4*)vbuf[cur][1];

        #pragma unroll 4
        for (int k4 = 0; k4 < K4PS; ++k4) {
            const float4* p = Wbase + (size_t)k4 * G4H;
            float4 w0 = p[0], w1 = p[1], w2 = p[2], w3 = p[3];  // gates i,f,c,o
            float4 v0 = vb0[K4PS * s + k4];
            float4 v1 = vb1[K4PS * s + k4];
            acc[0][0] = fmaf(w0.x, v0.x, fmaf(w0.y, v0.y, fmaf(w0.z, v0.z, fmaf(w0.w, v0.w, acc[0][0]))));
            acc[1][0] = fmaf(w1.x, v0.x, fmaf(w1.y, v0.y, fmaf(w1.z, v0.z, fmaf(w1.w, v0.w, acc[1][0]))));
            acc[2][0] = fmaf(w2.x, v0.x, fmaf(w2.y, v0.y, fmaf(w2.z, v0.z, fmaf(w2.w, v0.w, acc[2][0]))));
            acc[3][0] = fmaf(w3.x, v0.x, fmaf(w3.y, v0.y, fmaf(w3.z, v0.z, fmaf(w3.w, v0.w, acc[3][0]))));
            acc[0][1] = fmaf(w0.x, v1.x, fmaf(w0.y, v1.y, fmaf(w0.z, v1.z, fmaf(w0.w, v1.w, acc[0][1]))));
            acc[1][1] = fmaf(w1.x, v1.x, fmaf(w1.y, v1.y, fmaf(w1.z, v1.z, fmaf(w1.w, v1.w, acc[1][1]))));
            acc[2][1] = fmaf(w2.x, v1.x, fmaf(w2.y, v1.y, fmaf(w2.z, v1.z, fmaf(w2.w, v1.w, acc[2][1]))));
            acc[3][1] = fmaf(w3.x, v1.x, fmaf(w3.y, v1.y, fmaf(w3.z, v1.z, fmaf(w3.w, v1.w, acc[3][1]))));
        }

        if (s) {
            #pragma unroll
            for (int g = 0; g < 4; ++g) {
                part[s - 1][0][g][u] = acc[g][0];
                part[s - 1][1][g][u] = acc[g][1];
            }
        }
        __syncthreads();   // partials visible; step t-1 readers of vbuf[cur^1] long done

        if (s == 0) {
            #pragma unroll
            for (int b = 0; b < 2; ++b) {
                float gi = acc[0][b] + part[0][b][0][u] + part[1][b][0][u] + part[2][b][0][u] + bI;
                float gf = acc[1][b] + part[0][b][1][u] + part[1][b][1][u] + part[2][b][1][u] + bF;
                float gg = acc[2][b] + part[0][b][2][u] + part[1][b][2][u] + part[2][b][2][u] + bG;
                float go = acc[3][b] + part[0][b][3][u] + part[1][b][3][u] + part[2][b][3][u] + bO;
                float c  = b ? c1 : c0;
                float i_ = sigmoidf(gi + pi * c);
                float f_ = sigmoidf(gf + pf * c);
                float g_ = tanhf(gg);
                float cy = f_ * c + i_ * g_;
                float o_ = sigmoidf(go + po * cy);
                float hy = o_ * tanhf(cy);
                if (b) c1 = cy; else c0 = cy;
                vbuf[cur ^ 1][b][I_DIM + u] = hy;
                hseq[((size_t)(b0 + b) * ST + toff + t) * H_DIM + u] = hy;
            }
        } else if (s == 1 && u < 32) {
            // prefetch x_{t+1} into the other buffer (disjoint from h region)
            int tt = t + 1;
            if (tt < T) {
                int bb = u >> 4, k4 = u & 15;
                float4 v = *(const float4*)(x + ((size_t)(b0 + bb) * T + tt) * I_DIM + 4 * k4);
                *((float4*)&vbuf[cur ^ 1][bb][4 * k4]) = v;
            }
        }
        __syncthreads();
        cur ^= 1;
    }
}

// ---------------------------------------------------------------------------
// fc1 split-K partial GEMM (unchanged)
// ---------------------------------------------------------------------------
__global__ __launch_bounds__(256) void fc1_partial(const float* __restrict__ hseq,
                                                   const float* __restrict__ w,
                                                   float* __restrict__ part) {
    const int s  = blockIdx.x;          // 0..NSLICE-1
    const int k0 = s * KC;
    const int kend = (k0 + KC < F1) ? (k0 + KC) : F1;

    __shared__ float As[KCH][129];      // As[k][b]
    __shared__ float Bs[KCH][129];      // Bs[k][j]

    const int tid = threadIdx.x;
    const int tx = tid & 15;            // j block
    const int ty = tid >> 4;            // b block

    float acc[8][8];
    #pragma unroll
    for (int i = 0; i < 8; ++i)
        #pragma unroll
        for (int j = 0; j < 8; ++j) acc[i][j] = 0.f;

    for (int kk = k0; kk < kend; kk += KCH) {
        #pragma unroll
        for (int r = 0; r < 16; ++r) {
            int idx = r * 256 + tid;    // 0..4095
            int row = idx >> 5;
            int k   = idx & 31;
            int gk  = kk + k;
            float av = (gk < F1) ? hseq[(size_t)row * F1 + gk] : 0.f;
            float bv = (gk < F1) ? w[(size_t)row * F1 + gk] : 0.f;
            As[k][row] = av;
            Bs[k][row] = bv;
        }
        __syncthreads();

        #pragma unroll 8
        for (int k = 0; k < KCH; ++k) {
            float av[8], bv[8];
            #pragma unroll
            for (int i = 0; i < 8; ++i) av[i] = As[k][ty * 8 + i];
            #pragma unroll
            for (int j = 0; j < 8; ++j) bv[j] = Bs[k][tx * 8 + j];
            #pragma unroll
            for (int i = 0; i < 8; ++i)
                #pragma unroll
                for (int j = 0; j < 8; ++j)
                    acc[i][j] = fmaf(av[i], bv[j], acc[i][j]);
        }
        __syncthreads();
    }

    float* dst = part + (size_t)s * (BATCH * 128);
    #pragma unroll
    for (int i = 0; i < 8; ++i)
        #pragma unroll
        for (int j = 0; j < 8; ++j)
            dst[(size_t)(ty * 8 + i) * 128 + (tx * 8 + j)] = acc[i][j];
}

__global__ __launch_bounds__(256) void fc1_reduce(const float* __restrict__ part,
                                                  const float* __restrict__ fc1_b,
                                                  float* __restrict__ out1) {
    int flat = blockIdx.x * 256 + threadIdx.x;     // 0..16383
    float sum = 0.f;
    for (int i = 0; i < NSLICE; ++i)
        sum += part[(size_t)i * (BATCH * 128) + flat];
    int j = flat & 127;
    sum += fc1_b[j];
    out1[flat] = fmaxf(sum, 0.f);
}

__global__ __launch_bounds__(128) void fc2_kernel(const float* __restrict__ out1,
                                                  const float* __restrict__ fcw,
                                                  const float* __restrict__ fcb,
                                                  float* __restrict__ out) {
    int b = blockIdx.x;
    __shared__ float ro[128];
    int tid = threadIdx.x;
    ro[tid] = out1[(size_t)b * 128 + tid];
    __syncthreads();
    if (tid < NC) {
        float s = fcb[tid];
        #pragma unroll 8
        for (int j = 0; j < 128; ++j)
            s = fmaf(ro[j], fcw[(size_t)tid * 128 + j], s);
        out[(size_t)b * NC + tid] = s;
    }
}

// ---------------------------------------------------------------------------
extern "C" void kernel_launch(void* const* d_in, const int* in_sizes, int n_in,
                              void* d_out, int out_size, void* d_ws, size_t ws_size,
                              hipStream_t stream) {
    const float* rr_x  = (const float*)d_in[0];
    const float* rr_wv = (const float*)d_in[1];
    const float* w_ih1 = (const float*)d_in[2];
    const float* w_hh1 = (const float*)d_in[3];
    const float* b_ih1 = (const float*)d_in[4];
    const float* b_hh1 = (const float*)d_in[5];
    const float* wci1  = (const float*)d_in[6];
    const float* wcf1  = (const float*)d_in[7];
    const float* wco1  = (const float*)d_in[8];
    const float* w_ih2 = (const float*)d_in[9];
    const float* w_hh2 = (const float*)d_in[10];
    const float* b_ih2 = (const float*)d_in[11];
    const float* b_hh2 = (const float*)d_in[12];
    const float* wci2  = (const float*)d_in[13];
    const float* wcf2  = (const float*)d_in[14];
    const float* wco2  = (const float*)d_in[15];
    const float* fc1_w = (const float*)d_in[16];
    const float* fc1_b = (const float*)d_in[17];
    const float* fc_w  = (const float*)d_in[18];
    const float* fc_b  = (const float*)d_in[19];
    float* out = (float*)d_out;

    char* ws = (char*)d_ws;
    size_t off = 0;
    float4* Wp   = (float4*)(ws + off); off += (size_t)2 * K4TOT * G4H * sizeof(float4);
    float*  bsum = (float*)(ws + off);  off += (size_t)2 * G4H * sizeof(float);
    float*  hseq = (float*)(ws + off);  off += (size_t)BATCH * F1 * sizeof(float);
    float*  part = (float*)(ws + off);  off += (size_t)NSLICE * BATCH * 128 * sizeof(float);
    float*  out1 = (float*)(ws + off);  off += (size_t)BATCH * 128 * sizeof(float);

    prep_pack<<<8, 256, 0, stream>>>(w_ih1, w_hh1, b_ih1, b_hh1,
                                     w_ih2, w_hh2, b_ih2, b_hh2, Wp, bsum);

    lstm_fused<<<128, 1024, 0, stream>>>(rr_x, rr_wv,
                                         wci1, wcf1, wco1, wci2, wcf2, wco2,
                                         Wp, bsum, hseq);

    fc1_partial<<<NSLICE, 256, 0, stream>>>(hseq, fc1_w, part);
    fc1_reduce<<<BATCH * 128 / 256, 256, 0, stream>>>(part, fc1_b, out1);
    fc2_kernel<<<BATCH, 128, 0, stream>>>(out1, fc_w, fc_b, out);
}